// Round 1
// baseline (1302.564 us; speedup 1.0000x reference)
//
#include <hip/hip_runtime.h>
#include <math.h>

#define D_EMB 768
#define SEQN 2048
#define NB 4
#define NH 12
#define HDIM 64
#define MTOT (NB*SEQN)   // 8192

// ---------------- GEMM: C[m][n] = A[m][:] . W[n][:] + bias[n] ----------------
// 128x128 tile, 256 threads, 8x8 micro-tile (2x2 blocks of 4x4), BK=32.
#define BK 32
#define LDP 132   // padded LDS stride (528 B = 33*16, b128-aligned, 2-way max)

struct GemmPtrs {
    const float* A;
    const float* W0; const float* W1; const float* W2;
    const float* b0; const float* b1; const float* b2;
    float* o0; float* o1; float* o2;
};

template<int QKV>
__global__ __launch_bounds__(256) void gemm128(GemmPtrs p) {
    __shared__ float As[BK][LDP];
    __shared__ float Bs[BK][LDP];
    const int tid = threadIdx.x;
    const int tx = tid & 15, ty = tid >> 4;
    const int m0 = blockIdx.x * 128;
    const int n0 = blockIdx.y * 128;
    const float* W; const float* bias; float* out;
    if (QKV) {
        const int z = blockIdx.z;
        W    = (z==0) ? p.W0 : (z==1) ? p.W1 : p.W2;
        bias = (z==0) ? p.b0 : (z==1) ? p.b1 : p.b2;
        out  = (z==0) ? p.o0 : (z==1) ? p.o1 : p.o2;
    } else { W = p.W0; bias = p.b0; out = p.o0; }

    float acc[8][8];
    #pragma unroll
    for (int i=0;i<8;i++)
        #pragma unroll
        for (int j=0;j<8;j++) acc[i][j]=0.f;

    const int srow = tid >> 3;        // 0..31
    const int skk4 = (tid & 7) * 4;   // 0,4,...,28

    for (int k0 = 0; k0 < D_EMB; k0 += BK) {
        __syncthreads();
        #pragma unroll
        for (int r=0;r<4;r++) {
            const int row = srow + 32*r;   // 0..127
            float4 v = *(const float4*)(p.A + (size_t)(m0+row)*D_EMB + k0 + skk4);
            As[skk4+0][row]=v.x; As[skk4+1][row]=v.y; As[skk4+2][row]=v.z; As[skk4+3][row]=v.w;
            float4 w = *(const float4*)(W + (size_t)(n0+row)*D_EMB + k0 + skk4);
            Bs[skk4+0][row]=w.x; Bs[skk4+1][row]=w.y; Bs[skk4+2][row]=w.z; Bs[skk4+3][row]=w.w;
        }
        __syncthreads();
        #pragma unroll
        for (int kk=0;kk<BK;kk++) {
            float4 a0 = *(const float4*)&As[kk][ty*4];
            float4 a1 = *(const float4*)&As[kk][64+ty*4];
            float4 b0 = *(const float4*)&Bs[kk][tx*4];
            float4 b1 = *(const float4*)&Bs[kk][64+tx*4];
            float a[8] = {a0.x,a0.y,a0.z,a0.w,a1.x,a1.y,a1.z,a1.w};
            float b[8] = {b0.x,b0.y,b0.z,b0.w,b1.x,b1.y,b1.z,b1.w};
            #pragma unroll
            for (int i=0;i<8;i++)
                #pragma unroll
                for (int j=0;j<8;j++)
                    acc[i][j] = fmaf(a[i], b[j], acc[i][j]);
        }
    }

    #pragma unroll
    for (int i=0;i<8;i++) {
        const int r = m0 + ((i<4) ? (ty*4+i) : (64 + ty*4 + (i-4)));
        #pragma unroll
        for (int j=0;j<8;j++) {
            const int c = n0 + ((j<4) ? (tx*4+j) : (64 + tx*4 + (j-4)));
            const float v = acc[i][j] + bias[c];
            if (QKV) {
                const int b = r >> 11, n = r & 2047, h = c >> 6, hd = c & 63;
                out[(((size_t)(b*NH + h))*SEQN + n)*HDIM + hd] = v;
            } else {
                out[(size_t)r*D_EMB + c] = v;
            }
        }
    }
}

// ---------------- Flash attention, fp32, 64 q-rows x 64 k-tile ----------------
#define ATILE 64
#define ALD 68   // padded stride (272 B = 17*16)

__global__ __launch_bounds__(256) void flash_attn(const float* __restrict__ Qg,
                                                  const float* __restrict__ Kg,
                                                  const float* __restrict__ Vg,
                                                  float* __restrict__ Og) {
    __shared__ float Qs[HDIM][ALD];   // [hd][q]
    __shared__ float Ks[HDIM][ALD];   // [hd][k]
    __shared__ float Vs[ATILE][ALD];  // [k][hd]
    __shared__ float Ps[ATILE][ALD];  // [k][q]
    const int tid = threadIdx.x;
    const int tx = tid & 15, ty = tid >> 4;
    const int qt = blockIdx.x;        // 0..31
    const int bh = blockIdx.y;        // 0..47
    const size_t base = (size_t)bh * SEQN * HDIM;
    const float scale = 0.125f;       // 1/sqrt(64)

    {   // stage Q transposed + scaled
        const int row = tid >> 2;           // 0..63
        const int cg  = (tid & 3) * 16;
        #pragma unroll
        for (int j=0;j<4;j++) {
            float4 v = *(const float4*)(Qg + base + (size_t)(qt*ATILE+row)*HDIM + cg + j*4);
            Qs[cg+j*4+0][row]=v.x*scale; Qs[cg+j*4+1][row]=v.y*scale;
            Qs[cg+j*4+2][row]=v.z*scale; Qs[cg+j*4+3][row]=v.w*scale;
        }
    }

    float m_run[4], l_run[4], o[4][4];
    #pragma unroll
    for (int i=0;i<4;i++){
        m_run[i]=-INFINITY; l_run[i]=0.f;
        #pragma unroll
        for(int j=0;j<4;j++) o[i][j]=0.f;
    }

    for (int kt=0; kt<SEQN/ATILE; kt++) {
        __syncthreads();
        {   // stage K transposed, V direct
            const int row = tid >> 2;
            const int cg  = (tid & 3)*16;
            #pragma unroll
            for (int j=0;j<4;j++) {
                float4 v = *(const float4*)(Kg + base + (size_t)(kt*ATILE+row)*HDIM + cg + j*4);
                Ks[cg+j*4+0][row]=v.x; Ks[cg+j*4+1][row]=v.y;
                Ks[cg+j*4+2][row]=v.z; Ks[cg+j*4+3][row]=v.w;
                float4 w = *(const float4*)(Vg + base + (size_t)(kt*ATILE+row)*HDIM + cg + j*4);
                *(float4*)&Vs[row][cg+j*4] = w;
            }
        }
        __syncthreads();

        float s[4][4];
        #pragma unroll
        for (int i=0;i<4;i++)
            #pragma unroll
            for (int j=0;j<4;j++) s[i][j]=0.f;
        #pragma unroll 8
        for (int kk=0;kk<HDIM;kk++) {
            float4 a = *(const float4*)&Qs[kk][ty*4];
            float4 b = *(const float4*)&Ks[kk][tx*4];
            float av[4]={a.x,a.y,a.z,a.w}, bv[4]={b.x,b.y,b.z,b.w};
            #pragma unroll
            for (int i=0;i<4;i++)
                #pragma unroll
                for (int j=0;j<4;j++)
                    s[i][j] = fmaf(av[i], bv[j], s[i][j]);
        }

        // online softmax (per q-row; rows owned by the 16 tx-lanes jointly)
        #pragma unroll
        for (int i=0;i<4;i++) {
            float rmax = fmaxf(fmaxf(s[i][0],s[i][1]), fmaxf(s[i][2],s[i][3]));
            #pragma unroll
            for (int msk=1; msk<16; msk<<=1) rmax = fmaxf(rmax, __shfl_xor(rmax, msk));
            const float mnew = fmaxf(m_run[i], rmax);
            const float corr = __expf(m_run[i]-mnew);
            float rsum = 0.f;
            #pragma unroll
            for (int j=0;j<4;j++) { s[i][j] = __expf(s[i][j]-mnew); rsum += s[i][j]; }
            #pragma unroll
            for (int msk=1; msk<16; msk<<=1) rsum += __shfl_xor(rsum, msk);
            l_run[i] = l_run[i]*corr + rsum;
            m_run[i] = mnew;
            #pragma unroll
            for (int j=0;j<4;j++) { o[i][j]*=corr; Ps[tx*4+j][ty*4+i]=s[i][j]; }
        }
        __syncthreads();

        #pragma unroll 8
        for (int k=0;k<ATILE;k++) {
            float4 a = *(const float4*)&Ps[k][ty*4];
            float4 b = *(const float4*)&Vs[k][tx*4];
            float av[4]={a.x,a.y,a.z,a.w}, bv[4]={b.x,b.y,b.z,b.w};
            #pragma unroll
            for (int i=0;i<4;i++)
                #pragma unroll
                for (int j=0;j<4;j++)
                    o[i][j] = fmaf(av[i], bv[j], o[i][j]);
        }
    }

    const int b = bh / NH, h = bh % NH;
    #pragma unroll
    for (int i=0;i<4;i++) {
        const float inv = 1.f / l_run[i];
        const int n = qt*ATILE + ty*4 + i;
        #pragma unroll
        for (int j=0;j<4;j++) {
            Og[((size_t)(b*SEQN + n))*D_EMB + h*HDIM + tx*4 + j] = o[i][j]*inv;
        }
    }
}

// ---------------- launch ----------------
extern "C" void kernel_launch(void* const* d_in, const int* in_sizes, int n_in,
                              void* d_out, int out_size, void* d_ws, size_t ws_size,
                              hipStream_t stream) {
    const float* x  = (const float*)d_in[0];
    const float* Wq = (const float*)d_in[1];
    const float* bq = (const float*)d_in[2];
    const float* Wk = (const float*)d_in[3];
    const float* bk = (const float*)d_in[4];
    const float* Wv = (const float*)d_in[5];
    const float* bv = (const float*)d_in[6];
    const float* Wo = (const float*)d_in[7];
    const float* bo = (const float*)d_in[8];

    float* ws = (float*)d_ws;
    const size_t per = (size_t)NB*NH*SEQN*HDIM;   // 6,291,456 floats
    float* Q  = ws;
    float* K  = ws + per;
    float* V  = ws + 2*per;
    float* AT = ws + 3*per;                       // (B,N,D) attention output

    GemmPtrs pq = { x, Wq, Wk, Wv, bq, bk, bv, Q, K, V };
    gemm128<1><<<dim3(MTOT/128, D_EMB/128, 3), dim3(256), 0, stream>>>(pq);

    flash_attn<<<dim3(SEQN/ATILE, NB*NH), dim3(256), 0, stream>>>(Q, K, V, AT);

    GemmPtrs po = { AT, Wo, nullptr, nullptr, bo, nullptr, nullptr, (float*)d_out, nullptr, nullptr };
    gemm128<0><<<dim3(MTOT/128, D_EMB/128, 1), dim3(256), 0, stream>>>(po);
}

// Round 3
// 434.421 us; speedup vs baseline: 2.9984x; 2.9984x over previous
//
#include <hip/hip_runtime.h>
#include <math.h>

#define D_EMB 768
#define SEQN 2048
#define NB 4
#define NH 12
#define HDIM 64
#define MTOT (NB*SEQN)   // 8192

typedef short sh4 __attribute__((ext_vector_type(4)));
typedef short bf16x8 __attribute__((ext_vector_type(8)));
typedef float f32x16 __attribute__((ext_vector_type(16)));

#define MFMA32(a,b,c) __builtin_amdgcn_mfma_f32_32x32x16_bf16((a),(b),(c),0,0,0)

__device__ __forceinline__ unsigned short f2bf(float f){
    unsigned u = __builtin_bit_cast(unsigned, f);
    u += 0x7fffu + ((u>>16)&1u);
    return (unsigned short)(u>>16);
}
__device__ __forceinline__ float bf2f(unsigned short h){
    unsigned u = ((unsigned)h)<<16;
    return __builtin_bit_cast(float, u);
}
__device__ __forceinline__ void split4(const float* a, sh4& h, sh4& l){
    #pragma unroll
    for (int e=0;e<4;e++){
        unsigned short hb = f2bf(a[e]);
        h[e] = (short)hb;
        l[e] = (short)f2bf(a[e] - bf2f(hb));
    }
}
__device__ __forceinline__ bf16x8 ldfrag(const short* p){
    sh4 a = *(const sh4*)p;
    sh4 b = *(const sh4*)(p+4);
    return __builtin_shufflevector(a,b,0,1,2,3,4,5,6,7);
}
__device__ __forceinline__ void packpair(float a, float b, unsigned& hi, unsigned& lo){
    unsigned short ha = f2bf(a); unsigned short la = f2bf(a - bf2f(ha));
    unsigned short hb = f2bf(b); unsigned short lb = f2bf(b - bf2f(hb));
    hi = (unsigned)ha | (((unsigned)hb)<<16);
    lo = (unsigned)la | (((unsigned)lb)<<16);
}

// ================= bf16x3 MFMA GEMM: C[m][n] = A[m][:].W[n][:] + bias =================
// 128x128 tile, BK=32, 4 waves (2x2 of 64x64), 32x32x16 MFMA, split precision.
struct GemmPtrs {
    const float* A;
    const float* W0; const float* W1; const float* W2;
    const float* b0; const float* b1; const float* b2;
    float* o0; float* o1; float* o2;
};

#define GPAD 36   // shorts per row (32 used), 72B stride

template<int QKV>
__global__ __launch_bounds__(256,3) void gemm_mfma(GemmPtrs p) {
    __shared__ __align__(16) short Ahi[128][GPAD];
    __shared__ __align__(16) short Alo[128][GPAD];
    __shared__ __align__(16) short Bhi[128][GPAD];
    __shared__ __align__(16) short Blo[128][GPAD];

    const int tid = threadIdx.x;
    const int l  = tid & 63, w = tid >> 6;
    const int lq = l & 31,  g = l >> 5;
    const int wm = w >> 1,  wn = w & 1;
    const int m0 = blockIdx.x * 128;
    const int n0 = blockIdx.y * 128;

    const float* W; const float* bias; float* out;
    if (QKV) {
        const int z = blockIdx.z;
        W    = (z==0) ? p.W0 : (z==1) ? p.W1 : p.W2;
        bias = (z==0) ? p.b0 : (z==1) ? p.b1 : p.b2;
        out  = (z==0) ? p.o0 : (z==1) ? p.o1 : p.o2;
    } else { W = p.W0; bias = p.b0; out = p.o0; }

    f32x16 acc[2][2];
    #pragma unroll
    for (int i=0;i<2;i++)
        #pragma unroll
        for (int j=0;j<2;j++)
            #pragma unroll
            for (int r=0;r<16;r++) acc[i][j][r] = 0.f;

    const int srow = tid >> 1;
    const int skb  = (tid & 1) * 16;

    for (int k0 = 0; k0 < D_EMB; k0 += 32) {
        __syncthreads();
        {
            const float* ap = p.A + (size_t)(m0+srow)*D_EMB + k0 + skb;
            const float* wp = W   + (size_t)(n0+srow)*D_EMB + k0 + skb;
            #pragma unroll
            for (int c=0;c<4;c++){
                float4 v = *(const float4*)(ap + 4*c);
                float a[4] = {v.x,v.y,v.z,v.w};
                sh4 h, lo; split4(a, h, lo);
                *(sh4*)&Ahi[srow][skb+4*c] = h;
                *(sh4*)&Alo[srow][skb+4*c] = lo;
                float4 u = *(const float4*)(wp + 4*c);
                float b[4] = {u.x,u.y,u.z,u.w};
                split4(b, h, lo);
                *(sh4*)&Bhi[srow][skb+4*c] = h;
                *(sh4*)&Blo[srow][skb+4*c] = lo;
            }
        }
        __syncthreads();
        #pragma unroll
        for (int kk=0;kk<2;kk++){
            const int kc = kk*16 + g*8;
            bf16x8 ah[2], al[2], bh[2], bl[2];
            #pragma unroll
            for (int i=0;i<2;i++){
                const int row = wm*64 + 32*i + lq;
                ah[i] = ldfrag(&Ahi[row][kc]);
                al[i] = ldfrag(&Alo[row][kc]);
            }
            #pragma unroll
            for (int j=0;j<2;j++){
                const int row = wn*64 + 32*j + lq;
                bh[j] = ldfrag(&Bhi[row][kc]);
                bl[j] = ldfrag(&Blo[row][kc]);
            }
            #pragma unroll
            for (int i=0;i<2;i++)
                #pragma unroll
                for (int j=0;j<2;j++){
                    acc[i][j] = MFMA32(ah[i], bh[j], acc[i][j]);
                    acc[i][j] = MFMA32(ah[i], bl[j], acc[i][j]);
                    acc[i][j] = MFMA32(al[i], bh[j], acc[i][j]);
                }
        }
    }

    // epilogue
    #pragma unroll
    for (int j=0;j<2;j++){
        const int c = n0 + wn*64 + 32*j + lq;
        const float bv = bias[c];
        #pragma unroll
        for (int i=0;i<2;i++){
            #pragma unroll
            for (int r=0;r<16;r++){
                const int m = m0 + wm*64 + 32*i + (r&3) + 8*(r>>2) + 4*g;
                const float v = acc[i][j][r] + bv;
                if (QKV) {
                    const int b = m >> 11, n = m & 2047, h = c >> 6, hd = c & 63;
                    out[(((size_t)(b*NH + h))*SEQN + n)*HDIM + hd] = v;
                } else {
                    out[(size_t)m*D_EMB + c] = v;
                }
            }
        }
    }
}

// ================= bf16x3 MFMA flash attention =================
// Block: 4 waves, 128 q-rows (32/wave), KB=64 keys/tile.
// S^T = K.Q^T  (lane&31 = q), online softmax per lane, O^T = V^T.P^T.
#define KB 64
#define KPAD 68

__global__ __launch_bounds__(256,3) void attn_mfma(const float* __restrict__ Qg,
                                                   const float* __restrict__ Kg,
                                                   const float* __restrict__ Vg,
                                                   float* __restrict__ Og) {
    __shared__ __align__(16) short Khi[KB][KPAD];
    __shared__ __align__(16) short Klo[KB][KPAD];
    __shared__ __align__(16) short Vthi[HDIM][KPAD];
    __shared__ __align__(16) short Vtlo[HDIM][KPAD];

    const int tid = threadIdx.x;
    const int l  = tid & 63, w = tid >> 6;
    const int lq = l & 31,  g = l >> 5;
    const int qt = blockIdx.x;
    const int bh = blockIdx.y;
    const size_t base = (size_t)bh * SEQN * HDIM;
    const int qrow = qt*128 + w*32 + lq;

    // ---- Q fragments (scaled, split) from global ----
    bf16x8 qh[4], ql[4];
    {
        const float* qp = Qg + base + (size_t)qrow*HDIM;
        #pragma unroll
        for (int kk=0;kk<4;kk++){
            float4 v0 = *(const float4*)(qp + kk*16 + g*8);
            float4 v1 = *(const float4*)(qp + kk*16 + g*8 + 4);
            float a[8] = {v0.x,v0.y,v0.z,v0.w,v1.x,v1.y,v1.z,v1.w};
            #pragma unroll
            for (int e=0;e<8;e++){
                const float s = a[e] * 0.125f;
                const unsigned short hb = f2bf(s);
                qh[kk][e] = (short)hb;
                ql[kk][e] = (short)f2bf(s - bf2f(hb));
            }
        }
    }

    f32x16 o0, o1;
    #pragma unroll
    for (int r=0;r<16;r++){ o0[r]=0.f; o1[r]=0.f; }
    float m_run = -INFINITY, l_run = 0.f;

    for (int kt=0; kt<SEQN/KB; kt++){
        __syncthreads();
        {   // stage K (rows, split)
            const int key  = tid >> 2;
            const int dblk = (tid & 3) * 16;
            const float* kp = Kg + base + (size_t)(kt*KB + key)*HDIM + dblk;
            #pragma unroll
            for (int c=0;c<4;c++){
                float4 v = *(const float4*)(kp + 4*c);
                float a[4] = {v.x,v.y,v.z,v.w};
                sh4 h, lo; split4(a, h, lo);
                *(sh4*)&Khi[key][dblk+4*c] = h;
                *(sh4*)&Klo[key][dblk+4*c] = lo;
            }
            // stage V^T (transpose + split)
            const int hd = tid & 63, kg = tid >> 6;
            const float* vp = Vg + base + (size_t)(kt*KB + kg*16)*HDIM + hd;
            #pragma unroll
            for (int c=0;c<4;c++){
                float a[4];
                #pragma unroll
                for (int e=0;e<4;e++) a[e] = vp[(size_t)(4*c+e)*HDIM];
                sh4 h, lo; split4(a, h, lo);
                *(sh4*)&Vthi[hd][kg*16+4*c] = h;
                *(sh4*)&Vtlo[hd][kg*16+4*c] = lo;
            }
        }
        __syncthreads();

        // ---- S^T = K . Q^T (two 32-key tiles) ----
        f32x16 s0, s1;
        #pragma unroll
        for (int r=0;r<16;r++){ s0[r]=0.f; s1[r]=0.f; }
        #pragma unroll
        for (int kk=0;kk<4;kk++){
            const int kc = kk*16 + g*8;
            bf16x8 a0h = ldfrag(&Khi[lq][kc]);
            bf16x8 a0l = ldfrag(&Klo[lq][kc]);
            bf16x8 a1h = ldfrag(&Khi[32+lq][kc]);
            bf16x8 a1l = ldfrag(&Klo[32+lq][kc]);
            s0 = MFMA32(a0h, qh[kk], s0);
            s0 = MFMA32(a0h, ql[kk], s0);
            s0 = MFMA32(a0l, qh[kk], s0);
            s1 = MFMA32(a1h, qh[kk], s1);
            s1 = MFMA32(a1h, ql[kk], s1);
            s1 = MFMA32(a1l, qh[kk], s1);
        }

        // ---- online softmax (lane owns q-col; partner = lane^32) ----
        float pm = s0[0];
        #pragma unroll
        for (int r=1;r<16;r++) pm = fmaxf(pm, s0[r]);
        #pragma unroll
        for (int r=0;r<16;r++) pm = fmaxf(pm, s1[r]);
        pm = fmaxf(pm, __shfl_xor(pm, 32));
        const float mnew = fmaxf(m_run, pm);
        const float corr = __expf(m_run - mnew);
        float rs = 0.f;
        #pragma unroll
        for (int r=0;r<16;r++){ s0[r] = __expf(s0[r]-mnew); rs += s0[r]; }
        #pragma unroll
        for (int r=0;r<16;r++){ s1[r] = __expf(s1[r]-mnew); rs += s1[r]; }
        rs += __shfl_xor(rs, 32);
        l_run = l_run*corr + rs;
        m_run = mnew;
        o0 = o0 * corr;
        o1 = o1 * corr;

        // ---- pack P to bf16 hi/lo pairs + exchange with partner lane ----
        // pk?[j] holds P keys {8*(j>>1) + 2*(j&1) + 4*g_src, +1} of its 32-key block.
        unsigned pk0h[8], pk0l[8], pk1h[8], pk1l[8];
        unsigned rk0h[8], rk0l[8], rk1h[8], rk1l[8];
        #pragma unroll
        for (int j=0;j<8;j++){
            packpair(s0[2*j], s0[2*j+1], pk0h[j], pk0l[j]);
            packpair(s1[2*j], s1[2*j+1], pk1h[j], pk1l[j]);
        }
        #pragma unroll
        for (int j=0;j<8;j++){
            rk0h[j] = (unsigned)__shfl_xor((int)pk0h[j], 32);
            rk0l[j] = (unsigned)__shfl_xor((int)pk0l[j], 32);
            rk1h[j] = (unsigned)__shfl_xor((int)pk1h[j], 32);
            rk1l[j] = (unsigned)__shfl_xor((int)pk1l[j], 32);
        }

        // ---- O^T += V^T . P^T ----
        // B-frag for k-block kk: lane needs keys 16*(kk&1) + 8*g + 2*wd {,+1}.
        // Solving the pair index: j = 4*(kk&1) + 2*g + (wd&1), source half g' = wd>>1.
        #pragma unroll
        for (int kk=0;kk<4;kk++){
            const unsigned* ph = (kk>>1) ? pk1h : pk0h;
            const unsigned* pl = (kk>>1) ? pk1l : pk0l;
            const unsigned* rh = (kk>>1) ? rk1h : rk0h;
            const unsigned* rl = (kk>>1) ? rk1l : rk0l;
            const int jb = 4*(kk&1);
            unsigned wh[4], wl[4];
            #pragma unroll
            for (int wd=0; wd<4; wd++){
                const int c = wd & 1;
                const bool srcown = ((wd>>1) == g);   // need source half g' = wd>>1
                // j = jb + 2*g + c, but keep array indices compile-time (rule #20):
                const unsigned ph_g0 = ph[jb+c],   ph_g1 = ph[jb+2+c];
                const unsigned pl_g0 = pl[jb+c],   pl_g1 = pl[jb+2+c];
                const unsigned rh_g0 = rh[jb+c],   rh_g1 = rh[jb+2+c];
                const unsigned rl_g0 = rl[jb+c],   rl_g1 = rl[jb+2+c];
                const unsigned own_h = g ? ph_g1 : ph_g0;
                const unsigned own_l = g ? pl_g1 : pl_g0;
                const unsigned par_h = g ? rh_g1 : rh_g0;
                const unsigned par_l = g ? rl_g1 : rl_g0;
                wh[wd] = srcown ? own_h : par_h;
                wl[wd] = srcown ? own_l : par_l;
            }
            bf16x8 pbh, pbl;
            #pragma unroll
            for (int wd=0; wd<4; wd++){
                pbh[2*wd]   = (short)(wh[wd] & 0xffff);
                pbh[2*wd+1] = (short)(wh[wd] >> 16);
                pbl[2*wd]   = (short)(wl[wd] & 0xffff);
                pbl[2*wd+1] = (short)(wl[wd] >> 16);
            }
            const int kc = kk*16 + g*8;
            bf16x8 v0h = ldfrag(&Vthi[lq][kc]);
            bf16x8 v0l = ldfrag(&Vtlo[lq][kc]);
            bf16x8 v1h = ldfrag(&Vthi[32+lq][kc]);
            bf16x8 v1l = ldfrag(&Vtlo[32+lq][kc]);
            o0 = MFMA32(v0h, pbh, o0);
            o0 = MFMA32(v0h, pbl, o0);
            o0 = MFMA32(v0l, pbh, o0);
            o1 = MFMA32(v1h, pbh, o1);
            o1 = MFMA32(v1h, pbl, o1);
            o1 = MFMA32(v1l, pbh, o1);
        }
    }

    // ---- epilogue: O^T regs -> (b,n,d), float4 along hd ----
    const float inv = 1.f / l_run;
    const int b = bh / NH, h = bh % NH;
    float* op = Og + ((size_t)(b*SEQN + qrow))*D_EMB + h*HDIM;
    #pragma unroll
    for (int rq=0; rq<4; rq++){
        float4 v0, v1;
        v0.x = o0[4*rq+0]*inv; v0.y = o0[4*rq+1]*inv;
        v0.z = o0[4*rq+2]*inv; v0.w = o0[4*rq+3]*inv;
        v1.x = o1[4*rq+0]*inv; v1.y = o1[4*rq+1]*inv;
        v1.z = o1[4*rq+2]*inv; v1.w = o1[4*rq+3]*inv;
        *(float4*)(op + 8*rq + 4*g)      = v0;
        *(float4*)(op + 32 + 8*rq + 4*g) = v1;
    }
}

// ================= launch =================
extern "C" void kernel_launch(void* const* d_in, const int* in_sizes, int n_in,
                              void* d_out, int out_size, void* d_ws, size_t ws_size,
                              hipStream_t stream) {
    const float* x  = (const float*)d_in[0];
    const float* Wq = (const float*)d_in[1];
    const float* bq = (const float*)d_in[2];
    const float* Wk = (const float*)d_in[3];
    const float* bk = (const float*)d_in[4];
    const float* Wv = (const float*)d_in[5];
    const float* bv = (const float*)d_in[6];
    const float* Wo = (const float*)d_in[7];
    const float* bo = (const float*)d_in[8];

    float* ws = (float*)d_ws;
    const size_t per = (size_t)NB*NH*SEQN*HDIM;
    float* Q  = ws;
    float* K  = ws + per;
    float* V  = ws + 2*per;
    float* AT = ws + 3*per;

    GemmPtrs pq = { x, Wq, Wk, Wv, bq, bk, bv, Q, K, V };
    gemm_mfma<1><<<dim3(MTOT/128, D_EMB/128, 3), dim3(256), 0, stream>>>(pq);

    attn_mfma<<<dim3(SEQN/128, NB*NH), dim3(256), 0, stream>>>(Q, K, V, AT);

    GemmPtrs po = { AT, Wo, nullptr, nullptr, bo, nullptr, nullptr, (float*)d_out, nullptr, nullptr };
    gemm_mfma<0><<<dim3(MTOT/128, D_EMB/128, 1), dim3(256), 0, stream>>>(po);
}

// Round 4
// 335.297 us; speedup vs baseline: 3.8848x; 1.2956x over previous
//
#include <hip/hip_runtime.h>
#include <math.h>

#define D_EMB 768
#define SEQN 2048
#define NB 4
#define NH 12
#define HDIM 64
#define MTOT (NB*SEQN)   // 8192
#define SCLQ 0.18033688011112042f   // 0.125 * log2(e)

typedef unsigned int u32;
typedef short sh4 __attribute__((ext_vector_type(4)));
typedef short bf16x8 __attribute__((ext_vector_type(8)));
typedef float f32x16 __attribute__((ext_vector_type(16)));

#define MFMA32(a,b,c) __builtin_amdgcn_mfma_f32_32x32x16_bf16((a),(b),(c),0,0,0)

// ---- packed format: u32 = bf16_hi(v) | bf16(v - hi)<<16 ----
__device__ __forceinline__ u32 cvtpk(float a, float b){
    u32 r; asm("v_cvt_pk_bf16_f32 %0, %1, %2" : "=v"(r) : "v"(a), "v"(b)); return r;
}
__device__ __forceinline__ u32 pack_split(float v){
    u32 h = cvtpk(v, v);                                   // low16 = bf16(v)
    float hf = __builtin_bit_cast(float, h << 16);
    float r = v - hf;
    u32 l = cvtpk(r, r);
    return __builtin_amdgcn_perm(l, h, 0x05040100u);       // h.lo16 | l.lo16<<16
}
__device__ __forceinline__ void unpack4(uint4 p, sh4& hi, sh4& lo){
    u32 h0 = __builtin_amdgcn_perm(p.y, p.x, 0x05040100u); // {x.lo16, y.lo16}
    u32 h1 = __builtin_amdgcn_perm(p.w, p.z, 0x05040100u);
    u32 l0 = __builtin_amdgcn_perm(p.y, p.x, 0x07060302u); // {x.hi16, y.hi16}
    u32 l1 = __builtin_amdgcn_perm(p.w, p.z, 0x07060302u);
    uint2 h = {h0, h1}, l = {l0, l1};
    hi = __builtin_bit_cast(sh4, h);
    lo = __builtin_bit_cast(sh4, l);
}
__device__ __forceinline__ bf16x8 ldfrag(const short* p){
    sh4 a = *(const sh4*)p;
    sh4 b = *(const sh4*)(p+4);
    return __builtin_shufflevector(a,b,0,1,2,3,4,5,6,7);
}
__device__ __forceinline__ bf16x8 cmb8(sh4 a, sh4 b){
    return __builtin_shufflevector(a,b,0,1,2,3,4,5,6,7);
}
// pack two P values into MFMA-pair format: hi = bf(a)|bf(b)<<16, lo = residuals
__device__ __forceinline__ void packpair(float a, float b, u32& hi, u32& lo){
    hi = cvtpk(a, b);
    float fa = __builtin_bit_cast(float, hi << 16);
    float fb = __builtin_bit_cast(float, hi & 0xffff0000u);
    lo = cvtpk(a - fa, b - fb);
}

// ================= prepass: fp32 -> packed planes =================
__global__ __launch_bounds__(256) void pack_one(const float* __restrict__ s, u32* __restrict__ d, int n4){
    int i = blockIdx.x*256 + threadIdx.x;
    if (i >= n4) return;
    float4 v = ((const float4*)s)[i];
    uint4 o = { pack_split(v.x), pack_split(v.y), pack_split(v.z), pack_split(v.w) };
    ((uint4*)d)[i] = o;
}
__global__ __launch_bounds__(256) void pack_w4(const float* __restrict__ w0, const float* __restrict__ w1,
                                               const float* __restrict__ w2, const float* __restrict__ w3,
                                               u32* __restrict__ d, int n4){
    const int z = blockIdx.y;
    const float* s = (z==0)?w0:(z==1)?w1:(z==2)?w2:w3;
    int i = blockIdx.x*256 + threadIdx.x;
    if (i >= n4) return;
    float4 v = ((const float4*)s)[i];
    uint4 o = { pack_split(v.x), pack_split(v.y), pack_split(v.z), pack_split(v.w) };
    ((uint4*)(d + (size_t)z*n4*4))[i] = o;
}

// ================= bf16x3 MFMA GEMM on packed inputs =================
#define GPAD 36   // shorts per LDS row (72B, 8B-aligned, 2-way-free banks)

struct GemmArgs {
    const u32* A;            // [M][768] packed
    const u32* W;            // 4 planes of [768][768] packed
    const float* b0; const float* b1; const float* b2;
    u32* oq; u32* ok; u32* ov;   // packed QKV outputs [bh][n][hd]
    float* of;                   // fp32 final output [M][768]
};

template<int QKV>
__global__ __launch_bounds__(256,3) void gemm_pk(GemmArgs p) {
    __shared__ __align__(16) short Ahi[128][GPAD];
    __shared__ __align__(16) short Alo[128][GPAD];
    __shared__ __align__(16) short Bhi[128][GPAD];
    __shared__ __align__(16) short Blo[128][GPAD];

    const int tid = threadIdx.x;
    const int l  = tid & 63, w = tid >> 6;
    const int lq = l & 31,  g = l >> 5;
    const int wm = w >> 1,  wn = w & 1;
    const int m0 = blockIdx.x * 128;
    const int n0 = blockIdx.y * 128;
    const int z  = QKV ? blockIdx.z : 3;
    const u32* W = p.W + (size_t)z * D_EMB * D_EMB;
    const float* bias = QKV ? (z==0 ? p.b0 : (z==1 ? p.b1 : p.b2)) : p.b0;

    f32x16 acc[2][2];
    #pragma unroll
    for (int i=0;i<2;i++)
        #pragma unroll
        for (int j=0;j<2;j++)
            #pragma unroll
            for (int r=0;r<16;r++) acc[i][j][r] = 0.f;

    const int srow = tid >> 1;
    const int skb  = (tid & 1) * 16;

    for (int k0 = 0; k0 < D_EMB; k0 += 32) {
        __syncthreads();
        {
            const u32* ap = p.A + (size_t)(m0+srow)*D_EMB + k0 + skb;
            const u32* wp = W   + (size_t)(n0+srow)*D_EMB + k0 + skb;
            #pragma unroll
            for (int c=0;c<4;c++){
                uint4 pa = *(const uint4*)(ap + 4*c);
                sh4 h, lo2; unpack4(pa, h, lo2);
                *(sh4*)&Ahi[srow][skb+4*c] = h;
                *(sh4*)&Alo[srow][skb+4*c] = lo2;
                uint4 pw = *(const uint4*)(wp + 4*c);
                unpack4(pw, h, lo2);
                *(sh4*)&Bhi[srow][skb+4*c] = h;
                *(sh4*)&Blo[srow][skb+4*c] = lo2;
            }
        }
        __syncthreads();
        #pragma unroll
        for (int kk=0;kk<2;kk++){
            const int kc = kk*16 + g*8;
            bf16x8 ah[2], al[2], bh[2], bl[2];
            #pragma unroll
            for (int i=0;i<2;i++){
                const int row = wm*64 + 32*i + lq;
                ah[i] = ldfrag(&Ahi[row][kc]);
                al[i] = ldfrag(&Alo[row][kc]);
            }
            #pragma unroll
            for (int j=0;j<2;j++){
                const int row = wn*64 + 32*j + lq;
                bh[j] = ldfrag(&Bhi[row][kc]);
                bl[j] = ldfrag(&Blo[row][kc]);
            }
            #pragma unroll
            for (int i=0;i<2;i++)
                #pragma unroll
                for (int j=0;j<2;j++){
                    acc[i][j] = MFMA32(ah[i], bh[j], acc[i][j]);
                    acc[i][j] = MFMA32(ah[i], bl[j], acc[i][j]);
                    acc[i][j] = MFMA32(al[i], bh[j], acc[i][j]);
                }
        }
    }

    // epilogue
    #pragma unroll
    for (int j=0;j<2;j++){
        const int c = n0 + wn*64 + 32*j + lq;
        const float bv = bias[c];
        #pragma unroll
        for (int i=0;i<2;i++){
            #pragma unroll
            for (int r=0;r<16;r++){
                const int m = m0 + wm*64 + 32*i + (r&3) + 8*(r>>2) + 4*g;
                float v = acc[i][j][r] + bv;
                if (QKV) {
                    if (z==0) v *= SCLQ;   // fold softmax scale * log2e into Q
                    const int b = m >> 11, n = m & 2047, h = c >> 6, hd = c & 63;
                    u32* outp = (z==0) ? p.oq : (z==1) ? p.ok : p.ov;
                    outp[(((size_t)(b*NH + h))*SEQN + n)*HDIM + hd] = pack_split(v);
                } else {
                    p.of[(size_t)m*D_EMB + c] = v;
                }
            }
        }
    }
}

// ================= bf16x3 MFMA flash attention on packed inputs =================
#define KB 64
#define KPAD 68

__global__ __launch_bounds__(256,3) void attn_pk(const u32* __restrict__ Qg,
                                                 const u32* __restrict__ Kg,
                                                 const u32* __restrict__ Vg,
                                                 u32* __restrict__ Og) {
    __shared__ __align__(16) short Khi[KB][KPAD];
    __shared__ __align__(16) short Klo[KB][KPAD];
    __shared__ __align__(16) short Vthi[HDIM][KPAD];
    __shared__ __align__(16) short Vtlo[HDIM][KPAD];

    const int tid = threadIdx.x;
    const int l  = tid & 63, w = tid >> 6;
    const int lq = l & 31,  g = l >> 5;
    const int qt = blockIdx.x;
    const int bh = blockIdx.y;
    const size_t base = (size_t)bh * SEQN * HDIM;
    const int qrow = qt*128 + w*32 + lq;

    // ---- Q fragments (pre-scaled + pre-split in GEMM) ----
    bf16x8 qh[4], ql[4];
    {
        const u32* qp = Qg + base + (size_t)qrow*HDIM;
        #pragma unroll
        for (int kk=0;kk<4;kk++){
            uint4 a = *(const uint4*)(qp + kk*16 + g*8);
            uint4 b = *(const uint4*)(qp + kk*16 + g*8 + 4);
            sh4 h0,l0,h1,l1;
            unpack4(a, h0, l0);
            unpack4(b, h1, l1);
            qh[kk] = cmb8(h0, h1);
            ql[kk] = cmb8(l0, l1);
        }
    }

    f32x16 o0, o1;
    #pragma unroll
    for (int r=0;r<16;r++){ o0[r]=0.f; o1[r]=0.f; }
    float m_run = -INFINITY, l_run = 0.f;

    for (int kt=0; kt<SEQN/KB; kt++){
        __syncthreads();
        {   // stage K rows (unpack only)
            const int key  = tid >> 2;
            const int dblk = (tid & 3) * 16;
            const u32* kp = Kg + base + (size_t)(kt*KB + key)*HDIM + dblk;
            #pragma unroll
            for (int c=0;c<4;c++){
                uint4 pk_ = *(const uint4*)(kp + 4*c);
                sh4 h, lo2; unpack4(pk_, h, lo2);
                *(sh4*)&Khi[key][dblk+4*c] = h;
                *(sh4*)&Klo[key][dblk+4*c] = lo2;
            }
            // stage V^T (coalesced column loads + unpack)
            const int hd = tid & 63, kg = tid >> 6;
            const u32* vp = Vg + base + (size_t)(kt*KB + kg*16)*HDIM + hd;
            #pragma unroll
            for (int c=0;c<4;c++){
                uint4 pp;
                pp.x = vp[(size_t)(4*c+0)*HDIM];
                pp.y = vp[(size_t)(4*c+1)*HDIM];
                pp.z = vp[(size_t)(4*c+2)*HDIM];
                pp.w = vp[(size_t)(4*c+3)*HDIM];
                sh4 h, lo2; unpack4(pp, h, lo2);
                *(sh4*)&Vthi[hd][kg*16+4*c] = h;
                *(sh4*)&Vtlo[hd][kg*16+4*c] = lo2;
            }
        }
        __syncthreads();

        // ---- S^T = K . Q^T (log2 domain) ----
        f32x16 s0, s1;
        #pragma unroll
        for (int r=0;r<16;r++){ s0[r]=0.f; s1[r]=0.f; }
        #pragma unroll
        for (int kk=0;kk<4;kk++){
            const int kc = kk*16 + g*8;
            bf16x8 a0h = ldfrag(&Khi[lq][kc]);
            bf16x8 a0l = ldfrag(&Klo[lq][kc]);
            bf16x8 a1h = ldfrag(&Khi[32+lq][kc]);
            bf16x8 a1l = ldfrag(&Klo[32+lq][kc]);
            s0 = MFMA32(a0h, qh[kk], s0);
            s0 = MFMA32(a0h, ql[kk], s0);
            s0 = MFMA32(a0l, qh[kk], s0);
            s1 = MFMA32(a1h, qh[kk], s1);
            s1 = MFMA32(a1h, ql[kk], s1);
            s1 = MFMA32(a1l, qh[kk], s1);
        }

        // ---- online softmax in exp2 domain (lane owns q-col; partner = lane^32) ----
        float pm = s0[0];
        #pragma unroll
        for (int r=1;r<16;r++) pm = fmaxf(pm, s0[r]);
        #pragma unroll
        for (int r=0;r<16;r++) pm = fmaxf(pm, s1[r]);
        pm = fmaxf(pm, __shfl_xor(pm, 32));
        const float mnew = fmaxf(m_run, pm);
        const float corr = __builtin_amdgcn_exp2f(m_run - mnew);
        float rs = 0.f;
        #pragma unroll
        for (int r=0;r<16;r++){ s0[r] = __builtin_amdgcn_exp2f(s0[r]-mnew); rs += s0[r]; }
        #pragma unroll
        for (int r=0;r<16;r++){ s1[r] = __builtin_amdgcn_exp2f(s1[r]-mnew); rs += s1[r]; }
        rs += __shfl_xor(rs, 32);
        l_run = l_run*corr + rs;
        m_run = mnew;
        o0 = o0 * corr;
        o1 = o1 * corr;

        // ---- pack P to bf16 hi/lo pairs + exchange with partner lane ----
        u32 pk0h[8], pk0l[8], pk1h[8], pk1l[8];
        u32 rk0h[8], rk0l[8], rk1h[8], rk1l[8];
        #pragma unroll
        for (int j=0;j<8;j++){
            packpair(s0[2*j], s0[2*j+1], pk0h[j], pk0l[j]);
            packpair(s1[2*j], s1[2*j+1], pk1h[j], pk1l[j]);
        }
        #pragma unroll
        for (int j=0;j<8;j++){
            rk0h[j] = (u32)__shfl_xor((int)pk0h[j], 32);
            rk0l[j] = (u32)__shfl_xor((int)pk0l[j], 32);
            rk1h[j] = (u32)__shfl_xor((int)pk1h[j], 32);
            rk1l[j] = (u32)__shfl_xor((int)pk1l[j], 32);
        }

        // ---- O^T += V^T . P^T  (verified mapping: j = jb + 2g + (wd&1), own iff (wd>>1)==g) ----
        #pragma unroll
        for (int kk=0;kk<4;kk++){
            const u32* ph = (kk>>1) ? pk1h : pk0h;
            const u32* pl = (kk>>1) ? pk1l : pk0l;
            const u32* rh = (kk>>1) ? rk1h : rk0h;
            const u32* rl = (kk>>1) ? rk1l : rk0l;
            const int jb = 4*(kk&1);
            u32 wh[4], wl[4];
            #pragma unroll
            for (int wd=0; wd<4; wd++){
                const int c = wd & 1;
                const bool srcown = ((wd>>1) == g);
                const u32 ph_g0 = ph[jb+c],   ph_g1 = ph[jb+2+c];
                const u32 pl_g0 = pl[jb+c],   pl_g1 = pl[jb+2+c];
                const u32 rh_g0 = rh[jb+c],   rh_g1 = rh[jb+2+c];
                const u32 rl_g0 = rl[jb+c],   rl_g1 = rl[jb+2+c];
                const u32 own_h = g ? ph_g1 : ph_g0;
                const u32 own_l = g ? pl_g1 : pl_g0;
                const u32 par_h = g ? rh_g1 : rh_g0;
                const u32 par_l = g ? rl_g1 : rl_g0;
                wh[wd] = srcown ? own_h : par_h;
                wl[wd] = srcown ? own_l : par_l;
            }
            bf16x8 pbh, pbl;
            #pragma unroll
            for (int wd=0; wd<4; wd++){
                pbh[2*wd]   = (short)(wh[wd] & 0xffff);
                pbh[2*wd+1] = (short)(wh[wd] >> 16);
                pbl[2*wd]   = (short)(wl[wd] & 0xffff);
                pbl[2*wd+1] = (short)(wl[wd] >> 16);
            }
            const int kc = kk*16 + g*8;
            bf16x8 v0h = ldfrag(&Vthi[lq][kc]);
            bf16x8 v0l = ldfrag(&Vtlo[lq][kc]);
            bf16x8 v1h = ldfrag(&Vthi[32+lq][kc]);
            bf16x8 v1l = ldfrag(&Vtlo[32+lq][kc]);
            o0 = MFMA32(v0h, pbh, o0);
            o0 = MFMA32(v0h, pbl, o0);
            o0 = MFMA32(v0l, pbh, o0);
            o1 = MFMA32(v1h, pbh, o1);
            o1 = MFMA32(v1h, pbl, o1);
            o1 = MFMA32(v1l, pbh, o1);
        }
    }

    // ---- epilogue: O^T regs -> packed AT (b,n,d) ----
    const float inv = 1.f / l_run;
    const int b = bh / NH, h = bh % NH;
    u32* op = Og + ((size_t)(b*SEQN + qrow))*D_EMB + h*HDIM;
    #pragma unroll
    for (int rq=0; rq<4; rq++){
        uint4 w0, w1;
        w0.x = pack_split(o0[4*rq+0]*inv); w0.y = pack_split(o0[4*rq+1]*inv);
        w0.z = pack_split(o0[4*rq+2]*inv); w0.w = pack_split(o0[4*rq+3]*inv);
        w1.x = pack_split(o1[4*rq+0]*inv); w1.y = pack_split(o1[4*rq+1]*inv);
        w1.z = pack_split(o1[4*rq+2]*inv); w1.w = pack_split(o1[4*rq+3]*inv);
        *(uint4*)(op + 8*rq + 4*g)      = w0;
        *(uint4*)(op + 32 + 8*rq + 4*g) = w1;
    }
}

// ================= launch =================
extern "C" void kernel_launch(void* const* d_in, const int* in_sizes, int n_in,
                              void* d_out, int out_size, void* d_ws, size_t ws_size,
                              hipStream_t stream) {
    const float* x  = (const float*)d_in[0];
    const float* Wq = (const float*)d_in[1];
    const float* bq = (const float*)d_in[2];
    const float* Wk = (const float*)d_in[3];
    const float* bk = (const float*)d_in[4];
    const float* Wv = (const float*)d_in[5];
    const float* bv = (const float*)d_in[6];
    const float* Wo = (const float*)d_in[7];
    const float* bo = (const float*)d_in[8];

    u32* ws = (u32*)d_ws;
    const size_t per = (size_t)NB*NH*SEQN*HDIM;   // 6,291,456
    u32* Xpk  = ws;
    u32* Qpk  = ws + per;
    u32* Kpk  = ws + 2*per;
    u32* Vpk  = ws + 3*per;
    u32* Wpk  = ws + 4*per;                       // 4 planes x 589,824
    u32* ATpk = Xpk;                              // reuse after QKV GEMM

    pack_one<<<dim3((int)(per/4/256)), dim3(256), 0, stream>>>(x, Xpk, (int)(per/4));
    pack_w4<<<dim3(576,4), dim3(256), 0, stream>>>(Wq, Wk, Wv, Wo, Wpk, 147456);

    GemmArgs gq = { Xpk, Wpk, bq, bk, bv, Qpk, Kpk, Vpk, nullptr };
    gemm_pk<1><<<dim3(MTOT/128, D_EMB/128, 3), dim3(256), 0, stream>>>(gq);

    attn_pk<<<dim3(SEQN/128, NB*NH), dim3(256), 0, stream>>>(Qpk, Kpk, Vpk, ATpk);

    GemmArgs go = { ATpk, Wpk, bo, nullptr, nullptr, nullptr, nullptr, nullptr, (float*)d_out };
    gemm_pk<0><<<dim3(MTOT/128, D_EMB/128, 1), dim3(256), 0, stream>>>(go);
}

// Round 5
// 275.829 us; speedup vs baseline: 4.7224x; 1.2156x over previous
//
#include <hip/hip_runtime.h>
#include <math.h>

#define D_EMB 768
#define SEQN 2048
#define NB 4
#define NH 12
#define HDIM 64
#define MTOT (NB*SEQN)   // 8192
#define SCLQ 0.18033688011112042f   // 0.125 * log2(e)

typedef unsigned int u32;
typedef short sh4 __attribute__((ext_vector_type(4)));
typedef short bf16x8 __attribute__((ext_vector_type(8)));
typedef float f32x16 __attribute__((ext_vector_type(16)));

#define MFMA32(a,b,c) __builtin_amdgcn_mfma_f32_32x32x16_bf16((a),(b),(c),0,0,0)

// ---- packed format: u32 = bf16_hi(v) | bf16(v - hi)<<16 ----
__device__ __forceinline__ u32 cvtpk(float a, float b){
    u32 r; asm("v_cvt_pk_bf16_f32 %0, %1, %2" : "=v"(r) : "v"(a), "v"(b)); return r;
}
__device__ __forceinline__ u32 pack_split(float v){
    u32 h = cvtpk(v, v);                                   // low16 = bf16(v)
    float hf = __builtin_bit_cast(float, h << 16);
    float r = v - hf;
    u32 l = cvtpk(r, r);
    return __builtin_amdgcn_perm(l, h, 0x05040100u);       // h.lo16 | l.lo16<<16
}
__device__ __forceinline__ void unpack4(uint4 p, sh4& hi, sh4& lo){
    u32 h0 = __builtin_amdgcn_perm(p.y, p.x, 0x05040100u); // {x.lo16, y.lo16}
    u32 h1 = __builtin_amdgcn_perm(p.w, p.z, 0x05040100u);
    u32 l0 = __builtin_amdgcn_perm(p.y, p.x, 0x07060302u); // {x.hi16, y.hi16}
    u32 l1 = __builtin_amdgcn_perm(p.w, p.z, 0x07060302u);
    uint2 h = {h0, h1}, l = {l0, l1};
    hi = __builtin_bit_cast(sh4, h);
    lo = __builtin_bit_cast(sh4, l);
}
__device__ __forceinline__ void unpack4hi(uint4 p, sh4& hi){
    u32 h0 = __builtin_amdgcn_perm(p.y, p.x, 0x05040100u);
    u32 h1 = __builtin_amdgcn_perm(p.w, p.z, 0x05040100u);
    uint2 h = {h0, h1};
    hi = __builtin_bit_cast(sh4, h);
}
__device__ __forceinline__ bf16x8 ldfrag(const short* p){
    sh4 a = *(const sh4*)p;
    sh4 b = *(const sh4*)(p+4);
    return __builtin_shufflevector(a,b,0,1,2,3,4,5,6,7);
}
__device__ __forceinline__ bf16x8 cmb8(sh4 a, sh4 b){
    return __builtin_shufflevector(a,b,0,1,2,3,4,5,6,7);
}

// ================= prepass: fp32 -> packed planes =================
__global__ __launch_bounds__(256) void pack_one(const float* __restrict__ s, u32* __restrict__ d, int n4){
    int i = blockIdx.x*256 + threadIdx.x;
    if (i >= n4) return;
    float4 v = ((const float4*)s)[i];
    uint4 o = { pack_split(v.x), pack_split(v.y), pack_split(v.z), pack_split(v.w) };
    ((uint4*)d)[i] = o;
}
__global__ __launch_bounds__(256) void pack_w4(const float* __restrict__ w0, const float* __restrict__ w1,
                                               const float* __restrict__ w2, const float* __restrict__ w3,
                                               u32* __restrict__ d, int n4){
    const int z = blockIdx.y;
    const float* s = (z==0)?w0:(z==1)?w1:(z==2)?w2:w3;
    int i = blockIdx.x*256 + threadIdx.x;
    if (i >= n4) return;
    float4 v = ((const float4*)s)[i];
    uint4 o = { pack_split(v.x), pack_split(v.y), pack_split(v.z), pack_split(v.w) };
    ((uint4*)(d + (size_t)z*n4*4))[i] = o;
}

// ================= bf16x3 MFMA GEMM on packed inputs (T14 reg-prefetch) =================
#define GPAD 36   // shorts per LDS row (72B, 2-way-free banks)

struct GemmArgs {
    const u32* A;            // [M][768] packed
    const u32* W;            // 4 planes of [768][768] packed
    const float* b0; const float* b1; const float* b2;
    u32* oq; u32* ok; u32* ov;   // packed QKV outputs [bh][n][hd]
    float* of;                   // fp32 final output [M][768]
};

template<int QKV>
__global__ __launch_bounds__(256,3) void gemm_pk(GemmArgs p) {
    __shared__ __align__(16) short Ahi[128][GPAD];
    __shared__ __align__(16) short Alo[128][GPAD];
    __shared__ __align__(16) short Bhi[128][GPAD];
    __shared__ __align__(16) short Blo[128][GPAD];

    const int tid = threadIdx.x;
    const int l  = tid & 63, w = tid >> 6;
    const int lq = l & 31,  g = l >> 5;
    const int wm = w >> 1,  wn = w & 1;
    const int m0 = blockIdx.x * 128;
    const int n0 = blockIdx.y * 128;
    const int z  = QKV ? blockIdx.z : 3;
    const u32* W = p.W + (size_t)z * D_EMB * D_EMB;
    const float* bias = QKV ? (z==0 ? p.b0 : (z==1 ? p.b1 : p.b2)) : p.b0;

    f32x16 acc[2][2];
    #pragma unroll
    for (int i=0;i<2;i++)
        #pragma unroll
        for (int j=0;j<2;j++)
            #pragma unroll
            for (int r=0;r<16;r++) acc[i][j][r] = 0.f;

    const int srow = tid >> 1;
    const int skb  = (tid & 1) * 16;
    const u32* ap0 = p.A + (size_t)(m0+srow)*D_EMB + skb;
    const u32* wp0 = W   + (size_t)(n0+srow)*D_EMB + skb;

    uint4 areg[4], wreg[4];
    #pragma unroll
    for (int c=0;c<4;c++){ areg[c] = *(const uint4*)(ap0 + 4*c); wreg[c] = *(const uint4*)(wp0 + 4*c); }

    for (int k0 = 0; k0 < D_EMB; k0 += 32) {
        __syncthreads();
        #pragma unroll
        for (int c=0;c<4;c++){
            sh4 h, lo2;
            unpack4(areg[c], h, lo2);
            *(sh4*)&Ahi[srow][skb+4*c] = h;
            *(sh4*)&Alo[srow][skb+4*c] = lo2;
            unpack4(wreg[c], h, lo2);
            *(sh4*)&Bhi[srow][skb+4*c] = h;
            *(sh4*)&Blo[srow][skb+4*c] = lo2;
        }
        if (k0 + 32 < D_EMB){
            const u32* ap = ap0 + k0 + 32;
            const u32* wp = wp0 + k0 + 32;
            #pragma unroll
            for (int c=0;c<4;c++){ areg[c] = *(const uint4*)(ap + 4*c); wreg[c] = *(const uint4*)(wp + 4*c); }
        }
        __syncthreads();
        #pragma unroll
        for (int kk=0;kk<2;kk++){
            const int kc = kk*16 + g*8;
            bf16x8 ah[2], al[2], bh[2], bl[2];
            #pragma unroll
            for (int i=0;i<2;i++){
                const int row = wm*64 + 32*i + lq;
                ah[i] = ldfrag(&Ahi[row][kc]);
                al[i] = ldfrag(&Alo[row][kc]);
            }
            #pragma unroll
            for (int j=0;j<2;j++){
                const int row = wn*64 + 32*j + lq;
                bh[j] = ldfrag(&Bhi[row][kc]);
                bl[j] = ldfrag(&Blo[row][kc]);
            }
            #pragma unroll
            for (int i=0;i<2;i++)
                #pragma unroll
                for (int j=0;j<2;j++){
                    acc[i][j] = MFMA32(ah[i], bh[j], acc[i][j]);
                    acc[i][j] = MFMA32(ah[i], bl[j], acc[i][j]);
                    acc[i][j] = MFMA32(al[i], bh[j], acc[i][j]);
                }
        }
    }

    // epilogue
    #pragma unroll
    for (int j=0;j<2;j++){
        const int c = n0 + wn*64 + 32*j + lq;
        const float bv = bias[c];
        #pragma unroll
        for (int i=0;i<2;i++){
            #pragma unroll
            for (int r=0;r<16;r++){
                const int m = m0 + wm*64 + 32*i + (r&3) + 8*(r>>2) + 4*g;
                float v = acc[i][j][r] + bv;
                if (QKV) {
                    if (z==0) v *= SCLQ;   // fold softmax scale * log2(e) into Q
                    const int b = m >> 11, n = m & 2047, h = c >> 6, hd = c & 63;
                    u32* outp = (z==0) ? p.oq : (z==1) ? p.ok : p.ov;
                    outp[(((size_t)(b*NH + h))*SEQN + n)*HDIM + hd] = pack_split(v);
                } else {
                    p.of[(size_t)m*D_EMB + c] = v;
                }
            }
        }
    }
}

// ================= flash attention: bf16x3 QK^T, pure-bf16 PV =================
#define KB 64
#define KPAD 68

__global__ __launch_bounds__(256,3) void attn_pk(const u32* __restrict__ Qg,
                                                 const u32* __restrict__ Kg,
                                                 const u32* __restrict__ Vg,
                                                 u32* __restrict__ Og) {
    __shared__ __align__(16) short Khi[KB][KPAD];
    __shared__ __align__(16) short Klo[KB][KPAD];
    __shared__ __align__(16) short Vthi[HDIM][KPAD];

    const int tid = threadIdx.x;
    const int l  = tid & 63, w = tid >> 6;
    const int lq = l & 31,  g = l >> 5;
    const int qt = blockIdx.x;
    const int bh = blockIdx.y;
    const size_t base = (size_t)bh * SEQN * HDIM;
    const int qrow = qt*128 + w*32 + lq;

    // staging index helpers
    const int key  = tid >> 2;             // 0..63 (K row)
    const int dblk = (tid & 3) * 16;       // 16 u32 along d
    const int hd   = tid & 63, kg = tid >> 6;
    const u32* kp0 = Kg + base + (size_t)key*HDIM + dblk;
    const u32* vp0 = Vg + base + (size_t)(kg*16)*HDIM + hd;

    // ---- Q fragments (pre-scaled + pre-split in GEMM) ----
    bf16x8 qh[4], ql[4];
    {
        const u32* qp = Qg + base + (size_t)qrow*HDIM;
        #pragma unroll
        for (int kk=0;kk<4;kk++){
            uint4 a = *(const uint4*)(qp + kk*16 + g*8);
            uint4 b = *(const uint4*)(qp + kk*16 + g*8 + 4);
            sh4 h0,l0,h1,l1;
            unpack4(a, h0, l0);
            unpack4(b, h1, l1);
            qh[kk] = cmb8(h0, h1);
            ql[kk] = cmb8(l0, l1);
        }
    }

    f32x16 o0, o1;
    #pragma unroll
    for (int r=0;r<16;r++){ o0[r]=0.f; o1[r]=0.f; }
    float m_run = -INFINITY, l_run = 0.f;

    // T14 prefetch: tile 0 loads into regs
    uint4 kreg[4];
    u32 vreg[16];
    #pragma unroll
    for (int c=0;c<4;c++) kreg[c] = *(const uint4*)(kp0 + 4*c);
    #pragma unroll
    for (int i2=0;i2<16;i2++) vreg[i2] = vp0[(size_t)i2*HDIM];

    for (int kt=0; kt<SEQN/KB; kt++){
        __syncthreads();                       // prev tile's readers done
        {   // write LDS from prefetched regs (unpack only)
            #pragma unroll
            for (int c=0;c<4;c++){
                sh4 h, lo2; unpack4(kreg[c], h, lo2);
                *(sh4*)&Khi[key][dblk+4*c] = h;
                *(sh4*)&Klo[key][dblk+4*c] = lo2;
            }
            #pragma unroll
            for (int c=0;c<4;c++){
                uint4 pp = { vreg[4*c+0], vreg[4*c+1], vreg[4*c+2], vreg[4*c+3] };
                sh4 h; unpack4hi(pp, h);
                *(sh4*)&Vthi[hd][kg*16+4*c] = h;
            }
        }
        if (kt+1 < SEQN/KB){                   // issue next tile's loads (land during compute)
            const u32* kp = kp0 + (size_t)(kt+1)*KB*HDIM;
            const u32* vp = vp0 + (size_t)(kt+1)*KB*HDIM;
            #pragma unroll
            for (int c=0;c<4;c++) kreg[c] = *(const uint4*)(kp + 4*c);
            #pragma unroll
            for (int i2=0;i2<16;i2++) vreg[i2] = vp[(size_t)i2*HDIM];
        }
        __syncthreads();

        // ---- S^T = K . Q^T (log2 domain), bf16x3 ----
        f32x16 s0, s1;
        #pragma unroll
        for (int r=0;r<16;r++){ s0[r]=0.f; s1[r]=0.f; }
        __builtin_amdgcn_s_setprio(1);
        #pragma unroll
        for (int kk=0;kk<4;kk++){
            const int kc = kk*16 + g*8;
            bf16x8 a0h = ldfrag(&Khi[lq][kc]);
            bf16x8 a0l = ldfrag(&Klo[lq][kc]);
            bf16x8 a1h = ldfrag(&Khi[32+lq][kc]);
            bf16x8 a1l = ldfrag(&Klo[32+lq][kc]);
            s0 = MFMA32(a0h, qh[kk], s0);
            s0 = MFMA32(a0h, ql[kk], s0);
            s0 = MFMA32(a0l, qh[kk], s0);
            s1 = MFMA32(a1h, qh[kk], s1);
            s1 = MFMA32(a1h, ql[kk], s1);
            s1 = MFMA32(a1l, qh[kk], s1);
        }
        __builtin_amdgcn_s_setprio(0);

        // ---- online softmax, exp2 domain, T13 defer-max ----
        float pm = s0[0];
        #pragma unroll
        for (int r=1;r<16;r++) pm = fmaxf(pm, s0[r]);
        #pragma unroll
        for (int r=0;r<16;r++) pm = fmaxf(pm, s1[r]);
        pm = fmaxf(pm, __shfl_xor(pm, 32));
        const bool need = __any((int)(pm > m_run + 8.f));
        if (need){
            const float mnew = fmaxf(m_run, pm);
            const float corr = __builtin_amdgcn_exp2f(m_run - mnew);
            o0 = o0 * corr;
            o1 = o1 * corr;
            l_run = l_run * corr;
            m_run = mnew;
        }
        float rs = 0.f;
        #pragma unroll
        for (int r=0;r<16;r++){ s0[r] = __builtin_amdgcn_exp2f(s0[r]-m_run); rs += s0[r]; }
        #pragma unroll
        for (int r=0;r<16;r++){ s1[r] = __builtin_amdgcn_exp2f(s1[r]-m_run); rs += s1[r]; }
        rs += __shfl_xor(rs, 32);
        l_run += rs;

        // ---- pack P (hi only) + exchange with partner lane ----
        u32 pk0h[8], pk1h[8], rk0h[8], rk1h[8];
        #pragma unroll
        for (int j=0;j<8;j++){
            pk0h[j] = cvtpk(s0[2*j], s0[2*j+1]);
            pk1h[j] = cvtpk(s1[2*j], s1[2*j+1]);
        }
        #pragma unroll
        for (int j=0;j<8;j++){
            rk0h[j] = (u32)__shfl_xor((int)pk0h[j], 32);
            rk1h[j] = (u32)__shfl_xor((int)pk1h[j], 32);
        }

        // ---- O^T += V^T . P^T  (pure bf16; mapping j = jb + 2g + (wd&1), own iff (wd>>1)==g) ----
        __builtin_amdgcn_s_setprio(1);
        #pragma unroll
        for (int kk=0;kk<4;kk++){
            const u32* ph = (kk>>1) ? pk1h : pk0h;
            const u32* rh = (kk>>1) ? rk1h : rk0h;
            const int jb = 4*(kk&1);
            u32 wh[4];
            #pragma unroll
            for (int wd=0; wd<4; wd++){
                const int c = wd & 1;
                const bool srcown = ((wd>>1) == g);
                const u32 ph_g0 = ph[jb+c], ph_g1 = ph[jb+2+c];
                const u32 rh_g0 = rh[jb+c], rh_g1 = rh[jb+2+c];
                const u32 own_h = g ? ph_g1 : ph_g0;
                const u32 par_h = g ? rh_g1 : rh_g0;
                wh[wd] = srcown ? own_h : par_h;
            }
            uint4 whv = { wh[0], wh[1], wh[2], wh[3] };
            bf16x8 pbh = __builtin_bit_cast(bf16x8, whv);
            const int kc = kk*16 + g*8;
            bf16x8 v0h = ldfrag(&Vthi[lq][kc]);
            bf16x8 v1h = ldfrag(&Vthi[32+lq][kc]);
            o0 = MFMA32(v0h, pbh, o0);
            o1 = MFMA32(v1h, pbh, o1);
        }
        __builtin_amdgcn_s_setprio(0);
    }

    // ---- epilogue: O^T regs -> packed AT (b,n,d) ----
    const float inv = 1.f / l_run;
    const int b = bh / NH, h = bh % NH;
    u32* op = Og + ((size_t)(b*SEQN + qrow))*D_EMB + h*HDIM;
    #pragma unroll
    for (int rq=0; rq<4; rq++){
        uint4 w0, w1;
        w0.x = pack_split(o0[4*rq+0]*inv); w0.y = pack_split(o0[4*rq+1]*inv);
        w0.z = pack_split(o0[4*rq+2]*inv); w0.w = pack_split(o0[4*rq+3]*inv);
        w1.x = pack_split(o1[4*rq+0]*inv); w1.y = pack_split(o1[4*rq+1]*inv);
        w1.z = pack_split(o1[4*rq+2]*inv); w1.w = pack_split(o1[4*rq+3]*inv);
        *(uint4*)(op + 8*rq + 4*g)      = w0;
        *(uint4*)(op + 32 + 8*rq + 4*g) = w1;
    }
}

// ================= launch =================
extern "C" void kernel_launch(void* const* d_in, const int* in_sizes, int n_in,
                              void* d_out, int out_size, void* d_ws, size_t ws_size,
                              hipStream_t stream) {
    const float* x  = (const float*)d_in[0];
    const float* Wq = (const float*)d_in[1];
    const float* bq = (const float*)d_in[2];
    const float* Wk = (const float*)d_in[3];
    const float* bk = (const float*)d_in[4];
    const float* Wv = (const float*)d_in[5];
    const float* bv = (const float*)d_in[6];
    const float* Wo = (const float*)d_in[7];
    const float* bo = (const float*)d_in[8];

    u32* ws = (u32*)d_ws;
    const size_t per = (size_t)NB*NH*SEQN*HDIM;   // 6,291,456
    u32* Xpk  = ws;
    u32* Qpk  = ws + per;
    u32* Kpk  = ws + 2*per;
    u32* Vpk  = ws + 3*per;
    u32* Wpk  = ws + 4*per;                       // 4 planes x 589,824
    u32* ATpk = Xpk;                              // reuse after QKV GEMM

    pack_one<<<dim3((int)(per/4/256)), dim3(256), 0, stream>>>(x, Xpk, (int)(per/4));
    pack_w4<<<dim3(576,4), dim3(256), 0, stream>>>(Wq, Wk, Wv, Wo, Wpk, 147456);

    GemmArgs gq = { Xpk, Wpk, bq, bk, bv, Qpk, Kpk, Vpk, nullptr };
    gemm_pk<1><<<dim3(MTOT/128, D_EMB/128, 3), dim3(256), 0, stream>>>(gq);

    attn_pk<<<dim3(SEQN/128, NB*NH), dim3(256), 0, stream>>>(Qpk, Kpk, Vpk, ATpk);

    GemmArgs go = { ATpk, Wpk, bo, nullptr, nullptr, nullptr, nullptr, nullptr, (float*)d_out };
    gemm_pk<0><<<dim3(MTOT/128, D_EMB/128, 1), dim3(256), 0, stream>>>(go);
}